// Round 3
// baseline (836.899 us; speedup 1.0000x reference)
//
#include <hip/hip_runtime.h>
#include <math.h>

#define B_  2
#define C_  256
#define HS_ 64
#define WS_ 64
#define HF_ 128
#define WF_ 128
#define NH_ 8
#define HD_ 32
#define L_  4096           // 64*64 (both Lq and Lkv)
#define M_  (B_*L_)        // 8192

// ---------------------------------------------------------------------------
// kv[b][l][j] for j<256: j = c*9 + kh*3 + kw ; h=2*oh+kh-1, w=2*ow+kw-1
// (torch Unfold (3,3),s=2,p=1 then truncate channel-major dim to C)
// ---------------------------------------------------------------------------
__global__ __launch_bounds__(256) void build_kv_kernel(
    const float* __restrict__ feat, float* __restrict__ kv)
{
    int idx = blockIdx.x * 256 + threadIdx.x;   // B*L*C = 4M threads
    int j = idx & (C_ - 1);
    int l = (idx >> 8) & (L_ - 1);
    int b = idx >> 20;
    int c  = j / 9;
    int r  = j - c * 9;
    int kh = r / 3;
    int kw = r - kh * 3;
    int oh = l >> 6, ow = l & 63;
    int h = 2 * oh + kh - 1;
    int w = 2 * ow + kw - 1;
    float val = 0.0f;
    if ((unsigned)h < (unsigned)HF_ && (unsigned)w < (unsigned)WF_)
        val = feat[((size_t)(b * C_ + c) * HF_ + h) * WF_ + w];
    kv[idx] = val;
}

// ---------------------------------------------------------------------------
// out[m][n] = sum_c A[m][c] * W[n][c] + bias[n]
// TRANS_A: A element (m,c) lives at A[b*C*L + c*L + l]  (m = b*L + l)
// FUSE_OUT: write out[b*C*L + n*L + l] = (val+bias)*src[same]  (final gate)
// Tiles: BM=BN=64, BK=32, 256 threads, 4x4 per thread. LDS layout [k][row].
// ---------------------------------------------------------------------------
template <bool TRANS_A, bool FUSE_OUT>
__global__ __launch_bounds__(256) void gemm_kernel(
    const float* __restrict__ A, const float* __restrict__ W,
    const float* __restrict__ bias, float* __restrict__ out,
    const float* __restrict__ src)
{
    __shared__ float As[32][68];
    __shared__ float Ws[32][68];

    const int m0 = blockIdx.x * 64;
    const int n0 = blockIdx.y * 64;
    const int t  = threadIdx.x;
    const int tm = t >> 4;        // 0..15
    const int tn = t & 15;        // 0..15

    float acc[4][4] = {};

    for (int k0 = 0; k0 < C_; k0 += 32) {
        // ---- load A tile ----
        if (!TRANS_A) {
            #pragma unroll
            for (int u = t; u < 512; u += 256) {
                int row = u >> 3, c4 = u & 7;
                float4 val = *(const float4*)(A + (size_t)(m0 + row) * C_ + k0 + c4 * 4);
                As[c4 * 4 + 0][row] = val.x;
                As[c4 * 4 + 1][row] = val.y;
                As[c4 * 4 + 2][row] = val.z;
                As[c4 * 4 + 3][row] = val.w;
            }
        } else {
            int b  = m0 >> 12;          // tile never straddles batch (L%64==0)
            int l0 = m0 & (L_ - 1);
            #pragma unroll
            for (int u = t; u < 512; u += 256) {
                int c = u >> 4, l4 = u & 15;
                float4 val = *(const float4*)(A + (size_t)b * C_ * L_ +
                                              (size_t)(k0 + c) * L_ + l0 + l4 * 4);
                *(float4*)&As[c][l4 * 4] = val;
            }
        }
        // ---- load W tile ([n][k] row-major) ----
        #pragma unroll
        for (int u = t; u < 512; u += 256) {
            int row = u >> 3, c4 = u & 7;
            float4 val = *(const float4*)(W + (size_t)(n0 + row) * C_ + k0 + c4 * 4);
            Ws[c4 * 4 + 0][row] = val.x;
            Ws[c4 * 4 + 1][row] = val.y;
            Ws[c4 * 4 + 2][row] = val.z;
            Ws[c4 * 4 + 3][row] = val.w;
        }
        __syncthreads();
        #pragma unroll
        for (int kk = 0; kk < 32; kk++) {
            float4 a4 = *(float4*)&As[kk][tm * 4];
            float4 w4 = *(float4*)&Ws[kk][tn * 4];
            float a[4] = {a4.x, a4.y, a4.z, a4.w};
            float w[4] = {w4.x, w4.y, w4.z, w4.w};
            #pragma unroll
            for (int i = 0; i < 4; i++)
                #pragma unroll
                for (int jj = 0; jj < 4; jj++)
                    acc[i][jj] += a[i] * w[jj];
        }
        __syncthreads();
    }

    // ---- epilogue ----
    #pragma unroll
    for (int i = 0; i < 4; i++) {
        int m = m0 + tm * 4 + i;
        #pragma unroll
        for (int jj = 0; jj < 4; jj++) {
            int n = n0 + tn * 4 + jj;
            float val = acc[i][jj] + bias[n];
            if (FUSE_OUT) {
                int b = m >> 12, l = m & (L_ - 1);
                size_t oidx = (size_t)(b * C_ + n) * L_ + l;
                out[oidx] = val * src[oidx];
            } else {
                out[(size_t)m * C_ + n] = val;
            }
        }
    }
}

// ---------------------------------------------------------------------------
// Flash attention, fp32 VALU. Block = 64 query rows of one (b,h).
// 256 thr: row r = t>>2, lane-group g = t&3. Thread computes scores for keys
// kk = g + 4*j (j=0..15) [interleaved -> conflict-free LDS], and accumulates
// output dims d0 = g*8 .. +8.
// ---------------------------------------------------------------------------
__global__ __launch_bounds__(256) void attn_kernel(
    const float* __restrict__ q, const float* __restrict__ k,
    const float* __restrict__ v, float* __restrict__ o)
{
    __shared__ float Ks[64][36];
    __shared__ float Vs[64][36];
    __shared__ float Ps[64][68];

    const int qt = blockIdx.x;        // 0..63
    const int bh = blockIdx.y;        // 0..15
    const int b = bh >> 3, h = bh & 7;
    const int t = threadIdx.x;
    const int r = t >> 2;             // 0..63
    const int g = t & 3;              // 0..3
    const int d0 = g * 8;

    const size_t head_off = (size_t)b * L_ * C_ + h * HD_;

    // Q row -> registers
    float qreg[32];
    {
        const float* qrow = q + head_off + (size_t)(qt * 64 + r) * C_;
        #pragma unroll
        for (int d4 = 0; d4 < 8; d4++) {
            float4 val = *(const float4*)(qrow + d4 * 4);
            qreg[d4 * 4 + 0] = val.x; qreg[d4 * 4 + 1] = val.y;
            qreg[d4 * 4 + 2] = val.z; qreg[d4 * 4 + 3] = val.w;
        }
    }

    float acc[8] = {};
    float mrun = -INFINITY, lsum = 0.0f;
    const float scale = 0.17677669529663687f;   // 1/sqrt(32)

    for (int kt = 0; kt < 64; kt++) {
        __syncthreads();   // prior PV done -> safe to overwrite K/V
        #pragma unroll
        for (int u = t; u < 512; u += 256) {
            int row = u >> 3, d4 = u & 7;
            size_t goff = head_off + (size_t)(kt * 64 + row) * C_ + d4 * 4;
            *(float4*)&Ks[row][d4 * 4] = *(const float4*)(k + goff);
            *(float4*)&Vs[row][d4 * 4] = *(const float4*)(v + goff);
        }
        __syncthreads();

        // scores for this thread's 16 keys (kk = g + 4j)
        float s[16];
        float tmax = -INFINITY;
        #pragma unroll
        for (int j = 0; j < 16; j++) {
            int kk = g + 4 * j;
            float sum = 0.0f;
            #pragma unroll
            for (int d4 = 0; d4 < 8; d4++) {
                float4 k4 = *(float4*)&Ks[kk][d4 * 4];
                sum += qreg[d4 * 4 + 0] * k4.x + qreg[d4 * 4 + 1] * k4.y
                     + qreg[d4 * 4 + 2] * k4.z + qreg[d4 * 4 + 3] * k4.w;
            }
            s[j] = sum * scale;
            tmax = fmaxf(tmax, s[j]);
        }
        // row reduce over the 4 lane-groups (lanes 4r..4r+3 in one wave)
        tmax = fmaxf(tmax, __shfl_xor(tmax, 1));
        tmax = fmaxf(tmax, __shfl_xor(tmax, 2));
        float mnew = fmaxf(mrun, tmax);
        float psum = 0.0f;
        #pragma unroll
        for (int j = 0; j < 16; j++) {
            float p = __expf(s[j] - mnew);
            Ps[r][g + 4 * j] = p;
            psum += p;
        }
        psum += __shfl_xor(psum, 1);
        psum += __shfl_xor(psum, 2);
        float factor = __expf(mrun - mnew);
        lsum = lsum * factor + psum;
        mrun = mnew;
        #pragma unroll
        for (int i = 0; i < 8; i++) acc[i] *= factor;
        __syncthreads();   // Ps visible to whole block

        // PV: acc[d0..d0+8) += sum_k P[r][k] * V[k][d]
        #pragma unroll 8
        for (int kk = 0; kk < 64; kk++) {
            float pk = Ps[r][kk];
            float4 v0 = *(float4*)&Vs[kk][d0];
            float4 v1 = *(float4*)&Vs[kk][d0 + 4];
            acc[0] += pk * v0.x; acc[1] += pk * v0.y;
            acc[2] += pk * v0.z; acc[3] += pk * v0.w;
            acc[4] += pk * v1.x; acc[5] += pk * v1.y;
            acc[6] += pk * v1.z; acc[7] += pk * v1.w;
        }
    }

    float inv = 1.0f / lsum;
    float* orow = o + head_off + (size_t)(qt * 64 + r) * C_ + d0;
    #pragma unroll
    for (int i = 0; i < 8; i++) orow[i] = acc[i] * inv;
}

// ---------------------------------------------------------------------------
extern "C" void kernel_launch(void* const* d_in, const int* in_sizes, int n_in,
                              void* d_out, int out_size, void* d_ws, size_t ws_size,
                              hipStream_t stream)
{
    const float* feat = (const float*)d_in[0];
    const float* src  = (const float*)d_in[1];
    const float* Wq   = (const float*)d_in[2];
    const float* bq   = (const float*)d_in[3];
    const float* Wk   = (const float*)d_in[4];
    const float* bk   = (const float*)d_in[5];
    const float* Wv   = (const float*)d_in[6];
    const float* bv   = (const float*)d_in[7];
    const float* Wo   = (const float*)d_in[8];
    const float* bo   = (const float*)d_in[9];
    float* out = (float*)d_out;

    float* ws = (float*)d_ws;
    const size_t NE = (size_t)B_ * L_ * C_;   // 2M floats
    // Buffer plan (32 MB): kv dies after the V-projection; attention output
    // (ob) reuses its space.
    float* kv = ws;            // [B][L][C]   -> later reused as ob
    float* qb = ws + 1 * NE;   // [B][L][C]
    float* kb = ws + 2 * NE;
    float* vb = ws + 3 * NE;
    float* ob = kv;

    build_kv_kernel<<<(B_ * L_ * C_) / 256, 256, 0, stream>>>(feat, kv);

    dim3 ggrid(M_ / 64, C_ / 64);   // 128 x 4
    gemm_kernel<true,  false><<<ggrid, 256, 0, stream>>>(src, Wq, bq, qb, nullptr);
    gemm_kernel<false, false><<<ggrid, 256, 0, stream>>>(kv,  Wk, bk, kb, nullptr);
    gemm_kernel<false, false><<<ggrid, 256, 0, stream>>>(kv,  Wv, bv, vb, nullptr);

    attn_kernel<<<dim3(64, 16), 256, 0, stream>>>(qb, kb, vb, ob);

    gemm_kernel<false, true ><<<ggrid, 256, 0, stream>>>(ob, Wo, bo, out, src);
}

// Round 7
// 317.586 us; speedup vs baseline: 2.6352x; 2.6352x over previous
//
#include <hip/hip_runtime.h>
#include <math.h>

#define B_  2
#define C_  256
#define NH_ 8
#define HD_ 32
#define L_  4096           // 64*64 (both Lq and Lkv)
#define M_  (B_*L_)        // 8192

typedef __attribute__((ext_vector_type(8))) short bf16x8;
typedef __attribute__((ext_vector_type(4))) float f32x4;

// fp32 -> bf16 round-to-nearest-even (bit trick; values are tame, no NaN)
__device__ __forceinline__ unsigned short f2bf(float x) {
    unsigned u = __float_as_uint(x);
    unsigned r = u + 0x7fffu + ((u >> 16) & 1u);
    return (unsigned short)(r >> 16);
}

#define GLOAD_LDS16(gp, lp) \
    __builtin_amdgcn_global_load_lds( \
        (const __attribute__((address_space(1))) void*)(gp), \
        (__attribute__((address_space(3))) void*)(lp), 16, 0, 0)

// ---------------------------------------------------------------------------
// kv[b][l][j] for j<256: j = c*9 + kh*3 + kw ; h=2*oh+kh-1, w=2*ow+kw-1
// (torch Unfold (3,3),s=2,p=1 then truncate channel-major dim to C)
// ---------------------------------------------------------------------------
__global__ __launch_bounds__(256) void build_kv_kernel(
    const float* __restrict__ feat, float* __restrict__ kv)
{
    int idx = blockIdx.x * 256 + threadIdx.x;   // B*L*C = 4M threads
    int j = idx & (C_ - 1);
    int l = (idx >> 8) & (L_ - 1);
    int b = idx >> 20;
    int c  = j / 9;
    int r  = j - c * 9;
    int kh = r / 3;
    int kw = r - kh * 3;
    int oh = l >> 6, ow = l & 63;
    int h = 2 * oh + kh - 1;
    int w = 2 * ow + kw - 1;
    float val = 0.0f;
    if ((unsigned)h < 128u && (unsigned)w < 128u)
        val = feat[((size_t)(b * C_ + c) * 128 + h) * 128 + w];
    kv[idx] = val;
}

// ---------------------------------------------------------------------------
// out[m][n] = sum_c A[m][c] * W[n][c] + bias[n]
// TRANS_A: A element (m,c) at A[b*C*L + c*L + l]  (m = b*L + l)
// OMODE: 1 = bf16 row-major [m][256]
//        2 = bf16 transposed [b*256+n][key]   (V^T for attention)
//        3 = fp32 fused gate: out[b*C*L+n*L+l] = (val+bias)*src[same]
// ---------------------------------------------------------------------------
template <bool TRANS_A, int OMODE>
__global__ __launch_bounds__(256) void gemm_kernel(
    const float* __restrict__ A, const float* __restrict__ W,
    const float* __restrict__ bias, void* __restrict__ out,
    const float* __restrict__ src)
{
    __shared__ float As[32][68];
    __shared__ float Ws[32][68];

    const int m0 = blockIdx.x * 64;
    const int n0 = blockIdx.y * 64;
    const int t  = threadIdx.x;
    const int tm = t >> 4;        // 0..15
    const int tn = t & 15;        // 0..15

    float acc[4][4] = {};

    for (int k0 = 0; k0 < C_; k0 += 32) {
        if (!TRANS_A) {
            #pragma unroll
            for (int u = t; u < 512; u += 256) {
                int row = u >> 3, c4 = u & 7;
                float4 val = *(const float4*)(A + (size_t)(m0 + row) * C_ + k0 + c4 * 4);
                As[c4 * 4 + 0][row] = val.x;
                As[c4 * 4 + 1][row] = val.y;
                As[c4 * 4 + 2][row] = val.z;
                As[c4 * 4 + 3][row] = val.w;
            }
        } else {
            int b  = m0 >> 12;          // tile never straddles batch (L%64==0)
            int l0 = m0 & (L_ - 1);
            #pragma unroll
            for (int u = t; u < 512; u += 256) {
                int c = u >> 4, l4 = u & 15;
                float4 val = *(const float4*)(A + (size_t)b * C_ * L_ +
                                              (size_t)(k0 + c) * L_ + l0 + l4 * 4);
                *(float4*)&As[c][l4 * 4] = val;
            }
        }
        #pragma unroll
        for (int u = t; u < 512; u += 256) {
            int row = u >> 3, c4 = u & 7;
            float4 val = *(const float4*)(W + (size_t)(n0 + row) * C_ + k0 + c4 * 4);
            Ws[c4 * 4 + 0][row] = val.x;
            Ws[c4 * 4 + 1][row] = val.y;
            Ws[c4 * 4 + 2][row] = val.z;
            Ws[c4 * 4 + 3][row] = val.w;
        }
        __syncthreads();
        #pragma unroll
        for (int kk = 0; kk < 32; kk++) {
            float4 a4 = *(float4*)&As[kk][tm * 4];
            float4 w4 = *(float4*)&Ws[kk][tn * 4];
            float a[4] = {a4.x, a4.y, a4.z, a4.w};
            float w[4] = {w4.x, w4.y, w4.z, w4.w};
            #pragma unroll
            for (int i = 0; i < 4; i++)
                #pragma unroll
                for (int jj = 0; jj < 4; jj++)
                    acc[i][jj] += a[i] * w[jj];
        }
        __syncthreads();
    }

    if (OMODE == 1) {
        unsigned short* o = (unsigned short*)out;
        #pragma unroll
        for (int i = 0; i < 4; i++) {
            int m = m0 + tm * 4 + i;
            int n = n0 + tn * 4;
            ushort4 pk = make_ushort4(
                f2bf(acc[i][0] + bias[n + 0]), f2bf(acc[i][1] + bias[n + 1]),
                f2bf(acc[i][2] + bias[n + 2]), f2bf(acc[i][3] + bias[n + 3]));
            *(ushort4*)(o + ((size_t)m << 8) + n) = pk;
        }
    } else if (OMODE == 2) {
        unsigned short* o = (unsigned short*)out;
        int b = m0 >> 12;
        int key = (m0 & (L_ - 1)) + tm * 4;
        #pragma unroll
        for (int jj = 0; jj < 4; jj++) {
            int n = n0 + tn * 4 + jj;
            float bb = bias[n];
            ushort4 pk = make_ushort4(
                f2bf(acc[0][jj] + bb), f2bf(acc[1][jj] + bb),
                f2bf(acc[2][jj] + bb), f2bf(acc[3][jj] + bb));
            *(ushort4*)(o + ((size_t)(b * 256 + n) << 12) + key) = pk;
        }
    } else {   // OMODE == 3: fp32, fused * src, [b][n][l] layout
        float* o = (float*)out;
        #pragma unroll
        for (int i = 0; i < 4; i++) {
            int m = m0 + tm * 4 + i;
            int b = m >> 12, l = m & (L_ - 1);
            #pragma unroll
            for (int jj = 0; jj < 4; jj++) {
                int n = n0 + tn * 4 + jj;
                float val = acc[i][jj] + bias[n];
                size_t oidx = (size_t)(b * C_ + n) * L_ + l;
                o[oidx] = val * src[oidx];
            }
        }
    }
}

// ---------------------------------------------------------------------------
// MFMA flash attention (bf16 inputs, fp32 accum).
// Block = 4 waves x 16 q-rows = 64 q-rows of one (b,h). Swapped QK:
//   S^T[key][q] = mfma(A=K-frag, B=Q^T-frag)   (D: row=key=(l>>4)*4+i, col=q=l&15)
// Per-lane online softmax for column q=lane&15 (state replicated over l>>4).
// P^T redistributed to PV B-operand fully in registers (shfl), then
//   O^T[hd][q] = mfma(A=V^T-frag, B=P^T-frag), accumulated with rescale.
// Correctness is independent of the MFMA input k-slot permutation: QK pairs
// identical contiguous loads of the same hd axis; PV places the same key in
// paired A/B slots by construction. Only C/D layout (HW-verified) is assumed.
// ---------------------------------------------------------------------------
__global__ __launch_bounds__(256) void attn_mfma_kernel(
    const unsigned short* __restrict__ qbf,   // [M][256] bf16 row-major
    const unsigned short* __restrict__ kbf,   // [M][256] bf16 row-major
    const unsigned short* __restrict__ vbf,   // [B*256][4096] bf16 (V^T)
    float* __restrict__ ob)                   // [M][256] fp32 row-major
{
    __shared__ __align__(16) char Ksh[4096];
    __shared__ __align__(16) char Vsh[4096];

    // XCD-clustered decode: consecutive ids round-robin XCDs; each XCD sees
    // bh in {xcd, xcd+8} only -> per-XCD K/V working set ~1MB (L2-resident).
    const int id   = blockIdx.x;
    const int xcd  = id & 7;
    const int slot = id >> 3;
    const int bh   = xcd + 8 * (slot >> 6);
    const int qt   = slot & 63;
    const int b = bh >> 3, h = bh & 7;

    const int t    = threadIdx.x;
    const int w    = t >> 6;
    const int lane = t & 63;
    const int lg   = lane >> 4;   // 0..3
    const int lc   = lane & 15;   // 0..15

    // Q^T B-fragment: lane needs Q[hd=lg*8+j][q=qrow] = 16B of row-major Q
    const int qrow = qt * 64 + w * 16 + lc;
    const bf16x8 qf = *(const bf16x8*)(qbf + ((size_t)(b * L_ + qrow) << 8) + h * 32 + (lg << 3));

    // staging base addresses (bytes), advanced by kt per tile
    const char* kg = (const char*)kbf + ((size_t)(b * L_ + w * 16 + lc) << 9) + h * 64 + (lg << 4);
    const int vmt = t >> 7, vks = (t >> 6) & 1;
    const char* vg = (const char*)vbf + ((size_t)(b * 256 + h * 32 + vmt * 16 + lc) << 13)
                     + ((vks * 32 + (lg << 3)) << 1);

    f32x4 oacc[2];
    oacc[0] = (f32x4){0.f, 0.f, 0.f, 0.f};
    oacc[1] = (f32x4){0.f, 0.f, 0.f, 0.f};
    float mrun = -INFINITY, lrun = 0.0f;
    const float scale = 0.17677669529663687f;   // 1/sqrt(32)
    const f32x4 zero4 = (f32x4){0.f, 0.f, 0.f, 0.f};

    for (int kt = 0; kt < 64; kt++) {
        __syncthreads();   // all waves done reading previous tile
        GLOAD_LDS16(kg + (size_t)kt * 32768, Ksh + t * 16);
        GLOAD_LDS16(vg + (size_t)kt * 128,   Vsh + t * 16);
        __syncthreads();   // vmcnt(0) drained before barrier -> tiles ready

        // ---- S^T = K x Q^T : 4 key-group fragments ----
        f32x4 sa[4];
        #pragma unroll
        for (int f = 0; f < 4; f++) {
            bf16x8 kf = *(const bf16x8*)(Ksh + f * 1024 + lane * 16);
            sa[f] = __builtin_amdgcn_mfma_f32_16x16x32_bf16(kf, qf, zero4, 0, 0, 0);
        }

        // ---- online softmax for column q=lc (keys f*16 + lg*4 + i) ----
        float sv[16];
        float tmax = -INFINITY;
        #pragma unroll
        for (int f = 0; f < 4; f++)
            #pragma unroll
            for (int i = 0; i < 4; i++) {
                float x = sa[f][i] * scale;
                sv[f * 4 + i] = x;
                tmax = fmaxf(tmax, x);
            }
        tmax = fmaxf(tmax, __shfl_xor(tmax, 16));
        tmax = fmaxf(tmax, __shfl_xor(tmax, 32));
        float mnew   = fmaxf(mrun, tmax);
        float factor = __expf(mrun - mnew);
        float pv[16];
        float ps = 0.f;
        #pragma unroll
        for (int j2 = 0; j2 < 16; j2++) {
            float p = __expf(sv[j2] - mnew);
            pv[j2] = p;
            ps += p;
        }
        ps += __shfl_xor(ps, 16);
        ps += __shfl_xor(ps, 32);
        lrun = lrun * factor + ps;
        mrun = mnew;
        #pragma unroll
        for (int i = 0; i < 4; i++) { oacc[0][i] *= factor; oacc[1][i] *= factor; }

        // ---- pack P to bf16 pairs: W8[f*2+m] = keys f*16+lg*4+{2m,2m+1} ----
        unsigned W8[8];
        #pragma unroll
        for (int f = 0; f < 4; f++)
            #pragma unroll
            for (int m2 = 0; m2 < 2; m2++)
                W8[f * 2 + m2] = (unsigned)f2bf(pv[f * 4 + 2 * m2])
                               | ((unsigned)f2bf(pv[f * 4 + 2 * m2 + 1]) << 16);

        // ---- build P^T B-fragments in-register and do PV ----
        #pragma unroll
        for (int ks = 0; ks < 2; ks++) {
            union { unsigned u[4]; bf16x8 v; } bu;
            #pragma unroll
            for (int j = 0; j < 4; j++) {
                // word j needs keys ks*32 + lg*8 + 2j,2j+1 of column lc:
                // holder lane (g_h, lc), frag f = ks*2 + (lg>>1), word m = j&1
                int srcl = lc + 16 * ((lg & 1) * 2 + (j >> 1));
                unsigned va = (unsigned)__shfl((int)W8[(ks * 2) * 2 + (j & 1)], srcl);
                unsigned vb = (unsigned)__shfl((int)W8[(ks * 2 + 1) * 2 + (j & 1)], srcl);
                bu.u[j] = (lg >= 2) ? vb : va;
            }
            bf16x8 v0 = *(const bf16x8*)(Vsh + 0 * 2048 + ks * 1024 + lane * 16);
            bf16x8 v1 = *(const bf16x8*)(Vsh + 1 * 2048 + ks * 1024 + lane * 16);
            oacc[0] = __builtin_amdgcn_mfma_f32_16x16x32_bf16(v0, bu.v, oacc[0], 0, 0, 0);
            oacc[1] = __builtin_amdgcn_mfma_f32_16x16x32_bf16(v1, bu.v, oacc[1], 0, 0, 0);
        }
    }

    // ---- epilogue: O^T[hd][q=lc] / lrun -> ob[b*L+qrow][h*32+hd] fp32 ----
    float invl = 1.0f / lrun;
    #pragma unroll
    for (int mt = 0; mt < 2; mt++) {
        f32x4 ov = oacc[mt] * invl;
        // hd = mt*16 + lg*4 + {0..3} contiguous -> one aligned 16B store
        *(f32x4*)(ob + ((size_t)(b * L_ + qrow) << 8) + h * 32 + mt * 16 + (lg << 2)) = ov;
    }
}

// ---------------------------------------------------------------------------
extern "C" void kernel_launch(void* const* d_in, const int* in_sizes, int n_in,
                              void* d_out, int out_size, void* d_ws, size_t ws_size,
                              hipStream_t stream)
{
    const float* feat = (const float*)d_in[0];
    const float* src  = (const float*)d_in[1];
    const float* Wq   = (const float*)d_in[2];
    const float* bq   = (const float*)d_in[3];
    const float* Wk   = (const float*)d_in[4];
    const float* bk   = (const float*)d_in[5];
    const float* Wv   = (const float*)d_in[6];
    const float* bv   = (const float*)d_in[7];
    const float* Wo   = (const float*)d_in[8];
    const float* bo   = (const float*)d_in[9];
    float* out = (float*)d_out;

    float* ws = (float*)d_ws;
    const size_t NE = (size_t)M_ * C_;        // 2M elements
    // layout: kv fp32 (8MB) | ob fp32 (8MB) | qbf (4MB) | kbf (4MB) | vbf (4MB)
    float* kv = ws;
    float* ob = ws + NE;
    unsigned short* qbf = (unsigned short*)(ws + 2 * NE);
    unsigned short* kbf = qbf + NE;
    unsigned short* vbf = kbf + NE;

    build_kv_kernel<<<(B_ * L_ * C_) / 256, 256, 0, stream>>>(feat, kv);

    dim3 ggrid(M_ / 64, C_ / 64);   // 128 x 4
    gemm_kernel<true,  1><<<ggrid, 256, 0, stream>>>(src, Wq, bq, qbf, nullptr);
    gemm_kernel<false, 1><<<ggrid, 256, 0, stream>>>(kv,  Wk, bk, kbf, nullptr);
    gemm_kernel<false, 2><<<ggrid, 256, 0, stream>>>(kv,  Wv, bv, vbf, nullptr);

    attn_mfma_kernel<<<1024, 256, 0, stream>>>(qbf, kbf, vbf, ob);

    gemm_kernel<false, 3><<<ggrid, 256, 0, stream>>>(ob, Wo, bo, out, src);
}